// Round 4
// baseline (119.394 us; speedup 1.0000x reference)
//
#include <hip/hip_runtime.h>

// N=1536 T=20 H=64 E=16 M=128
// Qf[j,k] (MFMA-frag-tile layout), P[j,k]: fp16 in d_ws; W2f: pre-fragmented
// W2 (16KB fp16). out[i] = max_j relu( relu(Q[j]-P[i]) @ W2 + b2 )
//
// R8: kill the staging. Qf (384KB) is fully L2-resident (FETCH_SIZE 1.9MB),
// so LDS double-buffer + per-phase vmcnt(0)+barrier lockstep was pure
// overhead (R6/R7 both pinned at ~12 waves/CU, MfmaUtil ~30%, ~45% idle).
// Now: 1-wave blocks, NO LDS, NO barriers; Q tiles loaded straight from
// L1/L2 as 4x dwordx4 (frag layout => lane*16 contiguous, perfectly
// coalesced -- fixes R4's 64B/256B scatter); register qc/qn double-buffer
// hides L2 latency; W2 pre-fragmented by precompute so wave setup is 16
// vector loads instead of 128 scalar. Live set ~145 regs < 170 => 3
// waves/SIMD natural (R5 lesson: never force below live set). Grid
// 1536*2 = 3072 one-wave blocks = exactly 12 waves/CU, no tail.

#define NN 1536
#define HH 64
#define EE 16
#define MM 128
#define TT 20

#define JSPLIT 2
#define NTILE (96 / JSPLIT)   // 48 j-tiles of 16 per wave

typedef _Float16 half8 __attribute__((ext_vector_type(8)));
typedef float f32x4 __attribute__((ext_vector_type(4)));

// grid NN, block 128. Computes Qf (frag-tile layout), P, W2f, zero-inits out.
// Qf entry: A[row=j&15][k=m] for tile jt=j>>4 lands where reading lane
// l finds halfs jj at ((jt*4+ks)*64+l)*8+jj with k = ks*32 + (l>>4)*8 + jj
//   ->  ks=m>>5, l=((m>>3)&3)*16+(j&15), jj=m&7.   (verified passing R6/R7)
__global__ __launch_bounds__(128) void precompute_kernel(
    const float* __restrict__ hidden, const float* __restrict__ gt,
    const float* __restrict__ We, const float* __restrict__ be,
    const float* __restrict__ W1, const float* __restrict__ b1,
    const float* __restrict__ W2,
    _Float16* __restrict__ Qf, _Float16* __restrict__ P,
    _Float16* __restrict__ W2f, float* __restrict__ out)
{
  const int j = blockIdx.x;
  const int m = threadIdx.x;
  const float* hrow = hidden + j * HH;
  float a0 = 0.f, a1 = 0.f;
  #pragma unroll 8
  for (int h = 0; h < HH; h += 2) {
    a0 = fmaf(hrow[h],     W1[h * MM + m],       a0);
    a1 = fmaf(hrow[h + 1], W1[(h + 1) * MM + m], a1);
  }
  const float a = a0 + a1;
  float ve0 = 0.f, ve1 = 0.f, cm = b1[m];
  #pragma unroll
  for (int e = 0; e < EE; ++e) {
    float w1e = W1[(HH + e) * MM + m];
    ve0 = fmaf(We[e], w1e, ve0);       // We[0][e]
    ve1 = fmaf(We[EE + e], w1e, ve1);  // We[1][e]
    cm  = fmaf(be[e], w1e, cm);
  }
  const float e0 = gt[j * (2 * TT) + 2 * (TT - 1)];
  const float e1 = gt[j * (2 * TT) + 2 * (TT - 1) + 1];
  const float p = fmaf(e0, ve0, e1 * ve1);
  P[j * MM + m] = (_Float16)p;

  const int jt = j >> 4;
  const int ks = m >> 5;
  const int ln = ((m >> 3) & 3) * 16 + (j & 15);
  const int jj = m & 7;
  Qf[(((jt * 4) + ks) * 64 + ln) * 8 + jj] = (_Float16)(a + p + cm);

  if (m < HH) out[j * HH + m] = 0.f;

  // blocks 0..7: pre-fragment W2 -> W2f so pairmlp setup is 16 vector loads.
  // unit u = ct*256 + ksx*64 + l holds halfs jj with
  // W2f[u*8+jj] = (fp16) W2[(ksx*32 + (l>>4)*8 + jj)*HH + ct*16 + (l&15)]
  if (j < 8) {
    const int u = j * 128 + m;          // 0..1023
    const int ct = u >> 8;
    const int ksx = (u >> 6) & 3;
    const int l = u & 63;
    half8 w;
    #pragma unroll
    for (int t = 0; t < 8; ++t)
      w[t] = (_Float16)W2[(ksx * 32 + (l >> 4) * 8 + t) * HH + ct * 16 + (l & 15)];
    *(half8*)(W2f + (size_t)u * 8) = w;
  }
}

// grid NN*JSPLIT = 3072, block 64 (1 wave). Wave: i = bid%NN, js = bid/NN.
// Fully independent waves; Q tiles direct from L1/L2 with reg double-buffer.
__global__ __launch_bounds__(64, 3) void pairmlp_max_kernel(
    const _Float16* __restrict__ Qf, const _Float16* __restrict__ P,
    const _Float16* __restrict__ W2f, const float* __restrict__ b2,
    float* __restrict__ out)
{
  const int lane = threadIdx.x;
  const int quad = lane >> 4;
  const int lcol = lane & 15;
  const int i  = blockIdx.x % NN;   // consecutive blocks: same js -> same XCD
  const int js = blockIdx.x / NN;   // shares the same Q range in its L2

  // B fragments from pre-fragmented W2f: 16 coalesced 16B loads
  half8 bfrag[4][4];
  {
    const half8* wf = (const half8*)W2f + lane;
    #pragma unroll
    for (int ct = 0; ct < 4; ++ct)
      #pragma unroll
      for (int ks = 0; ks < 4; ++ks)
        bfrag[ct][ks] = wf[(ct * 4 + ks) * 64];
  }

  // P fragment for this wave's single i
  half8 pv[4];
  #pragma unroll
  for (int ks = 0; ks < 4; ++ks)
    pv[ks] = *(const half8*)(P + i * MM + ks * 32 + quad * 8);

  float b2v[4];
  #pragma unroll
  for (int ct = 0; ct < 4; ++ct) b2v[ct] = b2[ct * 16 + lcol];

  float rmax[4];
  #pragma unroll
  for (int ct = 0; ct < 4; ++ct) rmax[ct] = -3.0e38f;

  const int jt0 = js * NTILE;
  // tile = 256 half8 units (16 j x 128 k); lane-linear within (tile, ks)
  const half8* qbase = (const half8*)Qf + (size_t)jt0 * 256 + lane;

  // prefetch first tile into registers
  half8 qc[4], qn[4];
  #pragma unroll
  for (int ks = 0; ks < 4; ++ks) qc[ks] = qbase[ks * 64];

  const half8 hz = 0;

  for (int t = 0; t < NTILE; ++t) {
    // prefetch next tile (dummy re-load of tile 0 on last iter; unused)
    const int tn = (t + 1 < NTILE) ? (t + 1) : 0;
    #pragma unroll
    for (int ks = 0; ks < 4; ++ks)
      qn[ks] = qbase[(size_t)tn * 256 + ks * 64];

    f32x4 acc[4];
    // ks = 0 seeds the accumulators
    {
      half8 s = qc[0] - pv[0];
      s = __builtin_elementwise_max(s, hz);
      #pragma unroll
      for (int ct = 0; ct < 4; ++ct)
        acc[ct] = __builtin_amdgcn_mfma_f32_16x16x32_f16(s, bfrag[ct][0], f32x4{0.f, 0.f, 0.f, 0.f}, 0, 0, 0);
    }
    #pragma unroll
    for (int ks = 1; ks < 4; ++ks) {
      half8 s = qc[ks] - pv[ks];
      s = __builtin_elementwise_max(s, hz);
      #pragma unroll
      for (int ct = 0; ct < 4; ++ct)
        acc[ct] = __builtin_amdgcn_mfma_f32_16x16x32_f16(s, bfrag[ct][ks], acc[ct], 0, 0, 0);
    }

    // C/D: col=lcol+ct*16, row(j)=quad*4+reg. Raw max; +b2/relu deferred.
    #pragma unroll
    for (int ct = 0; ct < 4; ++ct) {
      const float m01 = fmaxf(acc[ct][0], acc[ct][1]);
      const float m23 = fmaxf(acc[ct][2], acc[ct][3]);
      rmax[ct] = fmaxf(rmax[ct], fmaxf(m01, m23));
    }

    #pragma unroll
    for (int ks = 0; ks < 4; ++ks) qc[ks] = qn[ks];
  }

  // combine quad-groups (different j rows, same col), then atomic max.
  #pragma unroll
  for (int ct = 0; ct < 4; ++ct) {
    float v = rmax[ct];
    v = fmaxf(v, __shfl_xor(v, 16, 64));
    v = fmaxf(v, __shfl_xor(v, 32, 64));
    v = fmaxf(v + b2v[ct], 0.f);
    if (quad == 0)
      atomicMax((unsigned*)(out + i * HH + ct * 16 + lcol), __float_as_uint(v));
  }
}

extern "C" void kernel_launch(void* const* d_in, const int* in_sizes, int n_in,
                              void* d_out, int out_size, void* d_ws, size_t ws_size,
                              hipStream_t stream) {
  const float* hidden = (const float*)d_in[0];
  const float* gt     = (const float*)d_in[1];
  const float* We     = (const float*)d_in[2];
  const float* be     = (const float*)d_in[3];
  const float* W1     = (const float*)d_in[4];
  const float* b1     = (const float*)d_in[5];
  const float* W2     = (const float*)d_in[6];
  const float* b2     = (const float*)d_in[7];
  float* out = (float*)d_out;

  _Float16* Qf  = (_Float16*)d_ws;     // NN*MM fp16 (384KB), frag-tile layout
  _Float16* Ph  = Qf + NN * MM;        // NN*MM fp16 (384KB)
  _Float16* W2f = Ph + NN * MM;        // 4*4*64*8 fp16 (16KB), frag layout

  precompute_kernel<<<NN, 128, 0, stream>>>(hidden, gt, We, be, W1, b1, W2, Qf, Ph, W2f, out);
  pairmlp_max_kernel<<<NN * JSPLIT, 64, 0, stream>>>(Qf, Ph, W2f, b2, out);
}

// Round 5
// 103.095 us; speedup vs baseline: 1.1581x; 1.1581x over previous
//
#include <hip/hip_runtime.h>

// N=1536 T=20 H=64 E=16 M=128
// Qf[j,k] (MFMA-frag-tile layout), P[j,k]: fp16 in d_ws; W2f: pre-fragmented
// W2 (16KB fp16). out[i] = max_j relu( relu(Q[j]-P[i]) @ W2 + b2 )
//
// R9: density over residency. Evidence R4-R8: observed residency saturates
// ~6-8 waves/CU and MfmaUtil pins 26-30% no matter the staging structure;
// best runs were the HIGH-DENSITY ones (R4: NI=3 -> 48 MFMA per 4 tile
// loads). So: R4's NI=3/CT=4 shape, minus R4's taxes:
//   - W2f pre-fragmented (16 vector loads replace 128 scalar + cvt)
//   - Q loads from frag layout: 4x dwordx4, lane*16B contiguous
//   - 2x-unrolled tile loop (no qc<-qn v_mov copies)
//   - max3-friendly rmax reduction (4->3 fmax per ct)
//   - s_setprio(1) around MFMA clusters (m191: +4-7% for independent
//     1-wave blocks; our exact case)
// Grid 512*4 = 2048 1-wave blocks = exactly 8 waves/CU at the honest
// 2 waves/SIMD footprint (live ~225 regs; R5 proved forcing 3/SIMD spills).

#define NN 1536
#define HH 64
#define EE 16
#define MM 128
#define TT 20

#define NI 3
#define NIGRP (NN / NI)       // 512 i-groups
#define JSPLIT 4
#define NTILE (96 / JSPLIT)   // 24 j-tiles of 16 per wave

typedef _Float16 half8 __attribute__((ext_vector_type(8)));
typedef float f32x4 __attribute__((ext_vector_type(4)));

// grid NN, block 128. Computes Qf (frag-tile layout), P, W2f, zero-inits out.
// Qf entry: A[row=j&15][k=m] for tile jt=j>>4 lands where reading lane
// l finds halfs jj at ((jt*4+ks)*64+l)*8+jj with k = ks*32 + (l>>4)*8 + jj
//   ->  ks=m>>5, l=((m>>3)&3)*16+(j&15), jj=m&7.   (verified R6-R8)
__global__ __launch_bounds__(128) void precompute_kernel(
    const float* __restrict__ hidden, const float* __restrict__ gt,
    const float* __restrict__ We, const float* __restrict__ be,
    const float* __restrict__ W1, const float* __restrict__ b1,
    const float* __restrict__ W2,
    _Float16* __restrict__ Qf, _Float16* __restrict__ P,
    _Float16* __restrict__ W2f, float* __restrict__ out)
{
  const int j = blockIdx.x;
  const int m = threadIdx.x;
  const float* hrow = hidden + j * HH;
  float a0 = 0.f, a1 = 0.f;
  #pragma unroll 8
  for (int h = 0; h < HH; h += 2) {
    a0 = fmaf(hrow[h],     W1[h * MM + m],       a0);
    a1 = fmaf(hrow[h + 1], W1[(h + 1) * MM + m], a1);
  }
  const float a = a0 + a1;
  float ve0 = 0.f, ve1 = 0.f, cm = b1[m];
  #pragma unroll
  for (int e = 0; e < EE; ++e) {
    float w1e = W1[(HH + e) * MM + m];
    ve0 = fmaf(We[e], w1e, ve0);       // We[0][e]
    ve1 = fmaf(We[EE + e], w1e, ve1);  // We[1][e]
    cm  = fmaf(be[e], w1e, cm);
  }
  const float e0 = gt[j * (2 * TT) + 2 * (TT - 1)];
  const float e1 = gt[j * (2 * TT) + 2 * (TT - 1) + 1];
  const float p = fmaf(e0, ve0, e1 * ve1);
  P[j * MM + m] = (_Float16)p;

  const int jt = j >> 4;
  const int ks = m >> 5;
  const int ln = ((m >> 3) & 3) * 16 + (j & 15);
  const int jj = m & 7;
  Qf[(((jt * 4) + ks) * 64 + ln) * 8 + jj] = (_Float16)(a + p + cm);

  if (m < HH) out[j * HH + m] = 0.f;

  // blocks 0..7: pre-fragment W2 -> W2f (verified R8).
  // unit u = ct*256 + ksx*64 + l holds halfs jj with
  // W2f[u*8+jj] = (fp16) W2[(ksx*32 + (l>>4)*8 + jj)*HH + ct*16 + (l&15)]
  if (j < 8) {
    const int u = j * 128 + m;          // 0..1023
    const int ct = u >> 8;
    const int ksx = (u >> 6) & 3;
    const int l = u & 63;
    half8 w;
    #pragma unroll
    for (int t = 0; t < 8; ++t)
      w[t] = (_Float16)W2[(ksx * 32 + (l >> 4) * 8 + t) * HH + ct * 16 + (l & 15)];
    *(half8*)(W2f + (size_t)u * 8) = w;
  }
}

// grid NIGRP*JSPLIT = 2048, block 64 (1 wave). Wave: i0..i0+2, 24 j-tiles.
// Fully independent waves; Q tiles direct from L1/L2; 48 MFMA per 4 loads.
__global__ __launch_bounds__(64, 2) void pairmlp_max_kernel(
    const _Float16* __restrict__ Qf, const _Float16* __restrict__ P,
    const _Float16* __restrict__ W2f, const float* __restrict__ b2,
    float* __restrict__ out)
{
  const int lane = threadIdx.x;
  const int quad = lane >> 4;
  const int lcol = lane & 15;
  const int ig = blockIdx.x % NIGRP;  // consecutive blocks: same js ->
  const int js = blockIdx.x / NIGRP;  // same Q tile stream (L1/L2 reuse)
  const int i0 = ig * NI;

  // B fragments from pre-fragmented W2f: 16 coalesced 16B loads
  half8 bfrag[4][4];
  {
    const half8* wf = (const half8*)W2f + lane;
    #pragma unroll
    for (int ct = 0; ct < 4; ++ct)
      #pragma unroll
      for (int ks = 0; ks < 4; ++ks)
        bfrag[ct][ks] = wf[(ct * 4 + ks) * 64];
  }

  // P fragments for NI i's
  half8 pv[NI][4];
  #pragma unroll
  for (int ii = 0; ii < NI; ++ii) {
    const _Float16* prow = P + (i0 + ii) * MM + quad * 8;
    #pragma unroll
    for (int ks = 0; ks < 4; ++ks)
      pv[ii][ks] = *(const half8*)(prow + ks * 32);
  }

  float b2v[4];
  #pragma unroll
  for (int ct = 0; ct < 4; ++ct) b2v[ct] = b2[ct * 16 + lcol];

  float rmax[NI][4];
  #pragma unroll
  for (int ii = 0; ii < NI; ++ii)
    #pragma unroll
    for (int ct = 0; ct < 4; ++ct) rmax[ii][ct] = -3.0e38f;

  const int jt0 = js * NTILE;
  // tile = 256 half8 units (16 j x 128 k); lane-linear within (tile, ks)
  const half8* qbase = (const half8*)Qf + (size_t)jt0 * 256 + lane;

  const half8 hz = 0;

  // compute one 16-j tile held in qt[4] against all NI i's
  auto compute_tile = [&](const half8* qt) {
    f32x4 acc[NI][4];
    #pragma unroll
    for (int ks = 0; ks < 4; ++ks) {
      __builtin_amdgcn_s_setprio(1);
      #pragma unroll
      for (int ii = 0; ii < NI; ++ii) {
        half8 s = qt[ks] - pv[ii][ks];
        s = __builtin_elementwise_max(s, hz);
        #pragma unroll
        for (int ct = 0; ct < 4; ++ct) {
          if (ks == 0)
            acc[ii][ct] = __builtin_amdgcn_mfma_f32_16x16x32_f16(
                s, bfrag[ct][0], f32x4{0.f, 0.f, 0.f, 0.f}, 0, 0, 0);
          else
            acc[ii][ct] = __builtin_amdgcn_mfma_f32_16x16x32_f16(
                s, bfrag[ct][ks], acc[ii][ct], 0, 0, 0);
        }
      }
      __builtin_amdgcn_s_setprio(0);
    }
    // C/D: col=lcol+ct*16, row(j)=quad*4+reg. Raw max; +b2/relu deferred.
    // max-of-4 written max3-friendly: v_max3 + v_max3 with rmax folded.
    #pragma unroll
    for (int ii = 0; ii < NI; ++ii)
      #pragma unroll
      for (int ct = 0; ct < 4; ++ct) {
        const float t3 = fmaxf(fmaxf(acc[ii][ct][0], acc[ii][ct][1]), acc[ii][ct][2]);
        rmax[ii][ct] = fmaxf(fmaxf(t3, acc[ii][ct][3]), rmax[ii][ct]);
      }
  };

  // prefetch tile 0 into qc
  half8 qc[4], qn[4];
  #pragma unroll
  for (int ks = 0; ks < 4; ++ks) qc[ks] = qbase[ks * 64];

  // 2x-unrolled ping-pong: no qc<-qn register copies
  for (int t = 0; t < NTILE; t += 2) {
    // prefetch tile t+1 into qn
    #pragma unroll
    for (int ks = 0; ks < 4; ++ks)
      qn[ks] = qbase[(size_t)(t + 1) * 256 + ks * 64];
    compute_tile(qc);  // tile t

    // prefetch tile t+2 into qc (dummy tile 0 on last pair; unused)
    const int t2 = (t + 2 < NTILE) ? (t + 2) : 0;
    #pragma unroll
    for (int ks = 0; ks < 4; ++ks)
      qc[ks] = qbase[(size_t)t2 * 256 + ks * 64];
    compute_tile(qn);  // tile t+1
  }

  // combine quad-groups (different j rows, same col), then atomic max.
  #pragma unroll
  for (int ii = 0; ii < NI; ++ii)
    #pragma unroll
    for (int ct = 0; ct < 4; ++ct) {
      float v = rmax[ii][ct];
      v = fmaxf(v, __shfl_xor(v, 16, 64));
      v = fmaxf(v, __shfl_xor(v, 32, 64));
      v = fmaxf(v + b2v[ct], 0.f);
      if (quad == 0)
        atomicMax((unsigned*)(out + (i0 + ii) * HH + ct * 16 + lcol), __float_as_uint(v));
    }
}

extern "C" void kernel_launch(void* const* d_in, const int* in_sizes, int n_in,
                              void* d_out, int out_size, void* d_ws, size_t ws_size,
                              hipStream_t stream) {
  const float* hidden = (const float*)d_in[0];
  const float* gt     = (const float*)d_in[1];
  const float* We     = (const float*)d_in[2];
  const float* be     = (const float*)d_in[3];
  const float* W1     = (const float*)d_in[4];
  const float* b1     = (const float*)d_in[5];
  const float* W2     = (const float*)d_in[6];
  const float* b2     = (const float*)d_in[7];
  float* out = (float*)d_out;

  _Float16* Qf  = (_Float16*)d_ws;     // NN*MM fp16 (384KB), frag-tile layout
  _Float16* Ph  = Qf + NN * MM;        // NN*MM fp16 (384KB)
  _Float16* W2f = Ph + NN * MM;        // 4*4*64*8 fp16 (16KB), frag layout

  precompute_kernel<<<NN, 128, 0, stream>>>(hidden, gt, We, be, W1, b1, W2, Qf, Ph, W2f, out);
  pairmlp_max_kernel<<<NIGRP * JSPLIT, 64, 0, stream>>>(Qf, Ph, W2f, b2, out);
}